// Round 1
// baseline (3177.914 us; speedup 1.0000x reference)
//
#include <hip/hip_runtime.h>

// context_mapping on MI355X.
// Layout: 1 thread = 1 x-quad (4 horizontally-adjacent pixels, sharing the LR pixel).
// 262144 threads = 1024 blocks x 256. Compute-bound fp32 VALU (~31us floor).

__device__ __forceinline__ float lrelu(float x) { return fmaxf(x, 0.01f * x); }

__global__ __launch_bounds__(256, 2) void ctx_map_kernel(
    const float* __restrict__ lr,  const float* __restrict__ hr,
    const float* __restrict__ w0g, const float* __restrict__ w1g,
    const float* __restrict__ w2g, const float* __restrict__ w3g,
    const float* __restrict__ s0g, const float* __restrict__ s1g,
    const float* __restrict__ s2g, const float* __restrict__ wfg,
    float* __restrict__ out)
{
    constexpr int H = 1024, W = 1024, C = 16;

    // Weights staged transposed: lwN[c][o] so the o-dimension is contiguous
    // -> float4 (ds_read_b128) broadcast reads, conflict-free (same addr all lanes).
    __shared__ __align__(16) float lw0[64 * 32];
    __shared__ __align__(16) float lw1[32 * 16];
    __shared__ __align__(16) float lw2[16 * 8];
    __shared__ float lsm[8 + 9 + 6 + 2 + 2];   // w3 | s0 | s1 | s2 | wf

    const int t = threadIdx.x;
    for (int i = t; i < 2048; i += 256) lw0[(i & 63) * 32 + (i >> 6)] = w0g[i];
    for (int i = t; i < 512;  i += 256) lw1[(i & 31) * 16 + (i >> 5)] = w1g[i];
    if (t < 128) lw2[(t & 15) * 8 + (t >> 4)] = w2g[t];
    if (t < 8)  lsm[t]      = w3g[t];
    if (t < 9)  lsm[8 + t]  = s0g[t];
    if (t < 6)  lsm[17 + t] = s1g[t];
    if (t < 2)  lsm[23 + t] = s2g[t];
    if (t < 2)  lsm[25 + t] = wfg[t];
    __syncthreads();

    const int gid = blockIdx.x * 256 + t;
    const int y   = gid >> 8;        // 256 quads per row
    const int xq  = gid & 255;
    const int x0  = xq << 2;

    // ---- LR channel values (shared by all 4 pixels of the quad) ----
    float l[C];
    const float* lrp = lr + (y >> 2) * 256 + xq;
    #pragma unroll
    for (int c = 0; c < C; ++c) l[c] = lrp[c * (256 * 256)];

    // ---- layer-1 bias: pure-LR term, computed once per quad ----
    float bias[32];
    #pragma unroll
    for (int o = 0; o < 32; ++o) bias[o] = 0.f;
    #pragma unroll
    for (int c = 0; c < C; ++c) {
        const float4* wa = (const float4*)&lw0[c * 32];
        #pragma unroll
        for (int o4 = 0; o4 < 8; ++o4) {
            float4 wv = wa[o4];
            bias[o4 * 4 + 0] += wv.x * l[c];
            bias[o4 * 4 + 1] += wv.y * l[c];
            bias[o4 * 4 + 2] += wv.z * l[c];
            bias[o4 * 4 + 3] += wv.w * l[c];
        }
    }

    float acc[32][4];
    #pragma unroll
    for (int o = 0; o < 32; ++o) {
        #pragma unroll
        for (int p = 0; p < 4; ++p) acc[o][p] = bias[o];
    }

    // ---- layer 1: hr / lr*hr / (lr-hr)^2 terms ----
    const float* hrp = hr + y * W + x0;
    #pragma unroll
    for (int c = 0; c < C; ++c) {
        const float4 h4 = *(const float4*)(hrp + c * (H * W));
        float hv[4] = {h4.x, h4.y, h4.z, h4.w};
        float lh[4], dd[4];
        #pragma unroll
        for (int p = 0; p < 4; ++p) {
            lh[p] = l[c] * hv[p];
            float d = l[c] - hv[p];
            dd[p] = d * d;
        }
        const float4* wB = (const float4*)&lw0[(16 + c) * 32];
        const float4* wC = (const float4*)&lw0[(32 + c) * 32];
        const float4* wD = (const float4*)&lw0[(48 + c) * 32];
        #pragma unroll
        for (int o4 = 0; o4 < 8; ++o4) {
            float4 wb = wB[o4], wc = wC[o4], wd = wD[o4];
            float wbv[4] = {wb.x, wb.y, wb.z, wb.w};
            float wcv[4] = {wc.x, wc.y, wc.z, wc.w};
            float wdv[4] = {wd.x, wd.y, wd.z, wd.w};
            #pragma unroll
            for (int k = 0; k < 4; ++k) {
                #pragma unroll
                for (int p = 0; p < 4; ++p) {
                    acc[o4 * 4 + k][p] += wbv[k] * hv[p] + wcv[k] * lh[p] + wdv[k] * dd[p];
                }
            }
        }
    }
    #pragma unroll
    for (int o = 0; o < 32; ++o) {
        #pragma unroll
        for (int p = 0; p < 4; ++p) acc[o][p] = lrelu(acc[o][p]);
    }

    // ---- layer 2: 32 -> 16 ----
    float a2[16][4];
    #pragma unroll
    for (int o = 0; o < 16; ++o) {
        #pragma unroll
        for (int p = 0; p < 4; ++p) a2[o][p] = 0.f;
    }
    #pragma unroll
    for (int i = 0; i < 32; ++i) {
        const float4* wv4 = (const float4*)&lw1[i * 16];
        #pragma unroll
        for (int o4 = 0; o4 < 4; ++o4) {
            float4 wv = wv4[o4];
            float wvv[4] = {wv.x, wv.y, wv.z, wv.w};
            #pragma unroll
            for (int k = 0; k < 4; ++k) {
                #pragma unroll
                for (int p = 0; p < 4; ++p) a2[o4 * 4 + k][p] += wvv[k] * acc[i][p];
            }
        }
    }
    #pragma unroll
    for (int o = 0; o < 16; ++o) {
        #pragma unroll
        for (int p = 0; p < 4; ++p) a2[o][p] = lrelu(a2[o][p]);
    }

    // ---- layer 3: 16 -> 8 ----
    float a3[8][4];
    #pragma unroll
    for (int o = 0; o < 8; ++o) {
        #pragma unroll
        for (int p = 0; p < 4; ++p) a3[o][p] = 0.f;
    }
    #pragma unroll
    for (int i = 0; i < 16; ++i) {
        const float4* wv4 = (const float4*)&lw2[i * 8];
        #pragma unroll
        for (int o4 = 0; o4 < 2; ++o4) {
            float4 wv = wv4[o4];
            float wvv[4] = {wv.x, wv.y, wv.z, wv.w};
            #pragma unroll
            for (int k = 0; k < 4; ++k) {
                #pragma unroll
                for (int p = 0; p < 4; ++p) a3[o4 * 4 + k][p] += wvv[k] * a2[i][p];
            }
        }
    }
    #pragma unroll
    for (int o = 0; o < 8; ++o) {
        #pragma unroll
        for (int p = 0; p < 4; ++p) a3[o][p] = lrelu(a3[o][p]);
    }

    // ---- layer 4: 8 -> 1 ----
    float wt1[4];
    #pragma unroll
    for (int p = 0; p < 4; ++p) {
        float s = 0.f;
        #pragma unroll
        for (int i = 0; i < 8; ++i) s += lsm[i] * a3[i][p];
        wt1[p] = lrelu(s);
    }

    // ---- weights2 branch (depends only on y%4 and p) + fuse ----
    const float xv0 = -2.f, xv1 = -1.f, xv2 = 1.f, xv3 = 2.f;
    const int yi = y & 3;
    const float d1 = (yi == 0) ? xv0 : (yi == 1) ? xv1 : (yi == 2) ? xv2 : xv3;
    const float awf0 = fabsf(lsm[25]);
    const float awf1 = fabsf(lsm[26]);

    float res[4];
    #pragma unroll
    for (int p = 0; p < 4; ++p) {
        const float d0 = (p == 0) ? xv0 : (p == 1) ? xv1 : (p == 2) ? xv2 : xv3;
        const float d2 = sqrtf(d0 * d0 + d1 * d1);
        float t0 = lrelu(lsm[8]  * d0 + lsm[9]  * d1 + lsm[10] * d2);
        float t1 = lrelu(lsm[11] * d0 + lsm[12] * d1 + lsm[13] * d2);
        float t2 = lrelu(lsm[14] * d0 + lsm[15] * d1 + lsm[16] * d2);
        float u0 = lrelu(lsm[17] * t0 + lsm[18] * t1 + lsm[19] * t2);
        float u1 = lrelu(lsm[20] * t0 + lsm[21] * t1 + lsm[22] * t2);
        float wt2 = lrelu(lsm[23] * u0 + lsm[24] * u1);
        res[p] = lrelu(awf0 * wt1[p] + awf1 * wt2);
    }
    *(float4*)(out + y * W + x0) = make_float4(res[0], res[1], res[2], res[3]);
}

extern "C" void kernel_launch(void* const* d_in, const int* in_sizes, int n_in,
                              void* d_out, int out_size, void* d_ws, size_t ws_size,
                              hipStream_t stream) {
    const float* lr = (const float*)d_in[0];
    const float* hr = (const float*)d_in[1];
    const float* w0 = (const float*)d_in[2];
    const float* w1 = (const float*)d_in[3];
    const float* w2 = (const float*)d_in[4];
    const float* w3 = (const float*)d_in[5];
    const float* s0 = (const float*)d_in[6];
    const float* s1 = (const float*)d_in[7];
    const float* s2 = (const float*)d_in[8];
    const float* wf = (const float*)d_in[9];
    float* o = (float*)d_out;

    // 1024*1024 pixels / 4 per thread = 262144 threads = 1024 blocks x 256
    ctx_map_kernel<<<1024, 256, 0, stream>>>(lr, hr, w0, w1, w2, w3, s0, s1, s2, wf, o);
}

// Round 2
// 173.721 us; speedup vs baseline: 18.2933x; 18.2933x over previous
//
#include <hip/hip_runtime.h>

// context_mapping on MI355X — round 2.
// 1 thread = 2 horizontally-adjacent pixels (same LR source pixel, scale=4).
// Per-thread live state kept < ~110 floats to avoid scratch spill (round-1 bug).
// 524288 threads = 2048 blocks x 256. fp32 VALU-bound, floor ~35us.

__device__ __forceinline__ float lrelu(float x) { return fmaxf(x, 0.01f * x); }

__global__ __launch_bounds__(256) void ctx_map_kernel(
    const float* __restrict__ lr,  const float* __restrict__ hr,
    const float* __restrict__ w0g, const float* __restrict__ w1g,
    const float* __restrict__ w2g, const float* __restrict__ w3g,
    const float* __restrict__ s0g, const float* __restrict__ s1g,
    const float* __restrict__ s2g, const float* __restrict__ wfg,
    float* __restrict__ out)
{
    constexpr int H = 1024, W = 1024, C = 16;

    // Weights transposed in LDS: lwN[c][o], o contiguous -> float4 broadcast reads.
    // Staged with LINEAR lds index (conflict-free ds_write); the transposed global
    // read is uncoalesced but weights are tiny and L2-resident.
    __shared__ __align__(16) float lw0[64 * 32];
    __shared__ __align__(16) float lw1[32 * 16];
    __shared__ __align__(16) float lw2[16 * 8];
    __shared__ float lsm[27];   // w3[8] | s0[9] | s1[6] | s2[2] | wf[2]

    const int t = threadIdx.x;
    for (int i = t; i < 2048; i += 256) lw0[i] = w0g[(i & 31) * 64 + (i >> 5)];
    for (int i = t; i < 512;  i += 256) lw1[i] = w1g[(i & 15) * 32 + (i >> 4)];
    if (t < 128) lw2[t] = w2g[(t & 7) * 16 + (t >> 3)];
    if (t < 8)  lsm[t]      = w3g[t];
    if (t < 9)  lsm[8 + t]  = s0g[t];
    if (t < 6)  lsm[17 + t] = s1g[t];
    if (t < 2)  lsm[23 + t] = s2g[t];
    if (t < 2)  lsm[25 + t] = wfg[t];
    __syncthreads();

    const int gid = blockIdx.x * 256 + t;
    const int y   = gid >> 9;        // 512 pixel-pairs per row
    const int xp  = gid & 511;
    const int x0  = xp << 1;         // even -> both pixels share lr quad

    // ---- LR channel values (shared by both pixels of the pair) ----
    float l[C];
    const float* lrp = lr + (y >> 2) * 256 + (x0 >> 2);
    #pragma unroll
    for (int c = 0; c < C; ++c) l[c] = lrp[c * (256 * 256)];

    // ---- layer 1 ----
    float acc[32][2];
    // pure-LR term accumulated once into acc[][0], then mirrored
    #pragma unroll
    for (int o = 0; o < 32; ++o) acc[o][0] = 0.f;
    #pragma unroll
    for (int c = 0; c < C; ++c) {
        const float4* wa = (const float4*)&lw0[c * 32];
        #pragma unroll
        for (int o4 = 0; o4 < 8; ++o4) {
            float4 wv = wa[o4];
            acc[o4 * 4 + 0][0] += wv.x * l[c];
            acc[o4 * 4 + 1][0] += wv.y * l[c];
            acc[o4 * 4 + 2][0] += wv.z * l[c];
            acc[o4 * 4 + 3][0] += wv.w * l[c];
        }
    }
    #pragma unroll
    for (int o = 0; o < 32; ++o) acc[o][1] = acc[o][0];

    // hr / lr*hr / (lr-hr)^2 terms
    const float* hrp = hr + y * W + x0;
    #pragma unroll
    for (int c = 0; c < C; ++c) {
        const float2 h2 = *(const float2*)(hrp + c * (H * W));
        float hv[2] = {h2.x, h2.y};
        float lh[2], dd[2];
        #pragma unroll
        for (int p = 0; p < 2; ++p) {
            lh[p] = l[c] * hv[p];
            float d = l[c] - hv[p];
            dd[p] = d * d;
        }
        const float4* wB = (const float4*)&lw0[(16 + c) * 32];
        const float4* wC = (const float4*)&lw0[(32 + c) * 32];
        const float4* wD = (const float4*)&lw0[(48 + c) * 32];
        #pragma unroll
        for (int o4 = 0; o4 < 8; ++o4) {
            float4 wb = wB[o4], wc = wC[o4], wd = wD[o4];
            float wbv[4] = {wb.x, wb.y, wb.z, wb.w};
            float wcv[4] = {wc.x, wc.y, wc.z, wc.w};
            float wdv[4] = {wd.x, wd.y, wd.z, wd.w};
            #pragma unroll
            for (int k = 0; k < 4; ++k) {
                #pragma unroll
                for (int p = 0; p < 2; ++p) {
                    acc[o4 * 4 + k][p] += wbv[k] * hv[p] + wcv[k] * lh[p] + wdv[k] * dd[p];
                }
            }
        }
    }
    #pragma unroll
    for (int o = 0; o < 32; ++o) {
        #pragma unroll
        for (int p = 0; p < 2; ++p) acc[o][p] = lrelu(acc[o][p]);
    }

    // ---- layer 2: 32 -> 16 ----
    float a2[16][2];
    #pragma unroll
    for (int o = 0; o < 16; ++o) { a2[o][0] = 0.f; a2[o][1] = 0.f; }
    #pragma unroll
    for (int i = 0; i < 32; ++i) {
        const float4* wv4 = (const float4*)&lw1[i * 16];
        #pragma unroll
        for (int o4 = 0; o4 < 4; ++o4) {
            float4 wv = wv4[o4];
            float wvv[4] = {wv.x, wv.y, wv.z, wv.w};
            #pragma unroll
            for (int k = 0; k < 4; ++k) {
                #pragma unroll
                for (int p = 0; p < 2; ++p) a2[o4 * 4 + k][p] += wvv[k] * acc[i][p];
            }
        }
    }
    #pragma unroll
    for (int o = 0; o < 16; ++o) {
        #pragma unroll
        for (int p = 0; p < 2; ++p) a2[o][p] = lrelu(a2[o][p]);
    }

    // ---- layer 3: 16 -> 8 ----
    float a3[8][2];
    #pragma unroll
    for (int o = 0; o < 8; ++o) { a3[o][0] = 0.f; a3[o][1] = 0.f; }
    #pragma unroll
    for (int i = 0; i < 16; ++i) {
        const float4* wv4 = (const float4*)&lw2[i * 8];
        #pragma unroll
        for (int o4 = 0; o4 < 2; ++o4) {
            float4 wv = wv4[o4];
            float wvv[4] = {wv.x, wv.y, wv.z, wv.w};
            #pragma unroll
            for (int k = 0; k < 4; ++k) {
                #pragma unroll
                for (int p = 0; p < 2; ++p) a3[o4 * 4 + k][p] += wvv[k] * a2[i][p];
            }
        }
    }
    #pragma unroll
    for (int o = 0; o < 8; ++o) {
        #pragma unroll
        for (int p = 0; p < 2; ++p) a3[o][p] = lrelu(a3[o][p]);
    }

    // ---- layer 4 (8->1) + weights2 branch + fuse ----
    const int yi = y & 3;
    const float d1 = (float)yi + ((yi < 2) ? -2.f : -1.f);   // {-2,-1,1,2}
    const float awf0 = fabsf(lsm[25]);
    const float awf1 = fabsf(lsm[26]);

    float res[2];
    #pragma unroll
    for (int p = 0; p < 2; ++p) {
        float s = 0.f;
        #pragma unroll
        for (int i = 0; i < 8; ++i) s += lsm[i] * a3[i][p];
        const float wt1 = lrelu(s);

        const int xi = (x0 + p) & 3;
        const float d0 = (float)xi + ((xi < 2) ? -2.f : -1.f);
        const float d2 = sqrtf(d0 * d0 + d1 * d1);
        float t0 = lrelu(lsm[8]  * d0 + lsm[9]  * d1 + lsm[10] * d2);
        float t1 = lrelu(lsm[11] * d0 + lsm[12] * d1 + lsm[13] * d2);
        float t2 = lrelu(lsm[14] * d0 + lsm[15] * d1 + lsm[16] * d2);
        float u0 = lrelu(lsm[17] * t0 + lsm[18] * t1 + lsm[19] * t2);
        float u1 = lrelu(lsm[20] * t0 + lsm[21] * t1 + lsm[22] * t2);
        float wt2 = lrelu(lsm[23] * u0 + lsm[24] * u1);
        res[p] = lrelu(awf0 * wt1 + awf1 * wt2);
    }
    *(float2*)(out + y * W + x0) = make_float2(res[0], res[1]);
}

extern "C" void kernel_launch(void* const* d_in, const int* in_sizes, int n_in,
                              void* d_out, int out_size, void* d_ws, size_t ws_size,
                              hipStream_t stream) {
    const float* lr = (const float*)d_in[0];
    const float* hr = (const float*)d_in[1];
    const float* w0 = (const float*)d_in[2];
    const float* w1 = (const float*)d_in[3];
    const float* w2 = (const float*)d_in[4];
    const float* w3 = (const float*)d_in[5];
    const float* s0 = (const float*)d_in[6];
    const float* s1 = (const float*)d_in[7];
    const float* s2 = (const float*)d_in[8];
    const float* wf = (const float*)d_in[9];
    float* o = (float*)d_out;

    // 1024*1024 pixels / 2 per thread = 524288 threads = 2048 blocks x 256
    ctx_map_kernel<<<2048, 256, 0, stream>>>(lr, hr, w0, w1, w2, w3, s0, s1, s2, wf, o);
}

// Round 4
// 142.571 us; speedup vs baseline: 22.2901x; 1.2185x over previous
//
#include <hip/hip_runtime.h>
#include <hip/hip_bf16.h>

// context_mapping on MI355X — round 3 (resubmit; round-3 bench died on
// GPUAcquisitionTimeout, no signal): bf16 MFMA chain.
// Per-pixel MLP as GEMM chain, orientation D = W * F (features=M, pixels=N),
// so the pixel index rides lane&15 through every layer (verified D layout).
// Inter-layer frag redistribution via 1KB per-wave LDS bounce (in-wave only,
// no barriers). k-layout assumption (k = 8*(lane>>4)+j) is applied identically
// to A and B frags -> result invariant to the true hardware k-ordering.

typedef __attribute__((ext_vector_type(8))) short bf16x8;
typedef __attribute__((ext_vector_type(4))) short s16x4;
typedef __attribute__((ext_vector_type(4))) float f32x4;

union B8 { bf16x8 v; short2 p[4]; };
union B4 { s16x4 v; short2 p[2]; };

__device__ __forceinline__ float lrelu(float x) { return fmaxf(x, 0.01f * x); }

__device__ __forceinline__ short2 cvt2(float a, float b) {
    __hip_bfloat162 h = __float22bfloat162_rn(make_float2(a, b));
    short2 s; __builtin_memcpy(&s, &h, 4); return s;
}

__global__ __launch_bounds__(256) void ctx_mfma(
    const float* __restrict__ lr,  const float* __restrict__ hr,
    const float* __restrict__ w0g, const float* __restrict__ w1g,
    const float* __restrict__ w2g, const float* __restrict__ w3g,
    const float* __restrict__ s0g, const float* __restrict__ s1g,
    const float* __restrict__ s2g, const float* __restrict__ wfg,
    float* __restrict__ out)
{
    constexpr int W = 1024, HW = 1024 * 1024, LHW = 256 * 256;
    __shared__ __align__(16) short zbuf[4][512];   // 1KB per wave

    const int tid  = threadIdx.x;
    const int lane = tid & 63;
    const int widx = tid >> 6;
    const int g    = lane >> 4;       // k-group 0..3
    const int px   = lane & 15;       // pixel-in-tile / weight-row index

    const int wave_id = blockIdx.x * 4 + widx;
    const int y  = wave_id >> 3;          // one row per 8 waves
    const int xw = (wave_id & 7) << 7;    // 128-px span

    // ---- weight A-fragments (A[m=px][k=8g+j]) ----
    B8 a1[2][2];                           // L1: [m-tile o0-15 / o16-31][k-chunk]
    #pragma unroll
    for (int m = 0; m < 2; ++m)
        #pragma unroll
        for (int q = 0; q < 2; ++q) {
            const float* wp = w0g + (m * 16 + px) * 64 + q * 32 + g * 8;
            #pragma unroll
            for (int j = 0; j < 4; ++j) a1[m][q].p[j] = cvt2(wp[2 * j], wp[2 * j + 1]);
        }
    B8 a2;                                 // L2: W1 [16 x 32]
    {
        const float* wp = w1g + px * 32 + g * 8;
        #pragma unroll
        for (int j = 0; j < 4; ++j) a2.p[j] = cvt2(wp[2 * j], wp[2 * j + 1]);
    }
    B8 a3;                                 // L3: W2 [8 x 16] zero-padded to [16 x 32]
    {
        const bool val = (px < 8) && (g < 2);
        const float* wp = w2g + (px & 7) * 16 + (g & 1) * 8;   // always in-bounds
        const short2 z2s = make_short2(0, 0);
        #pragma unroll
        for (int j = 0; j < 4; ++j) a3.p[j] = val ? cvt2(wp[2 * j], wp[2 * j + 1]) : z2s;
    }
    const float4 w3v = *(const float4*)(w3g + (g & 1) * 4);    // L4 slice per k-group

    // ---- loop-invariant distance-net (depends only on px&3 and y&3) ----
    const int xi = px & 3, yi = y & 3;
    const float d0 = (float)xi + ((xi < 2) ? -2.f : -1.f);
    const float d1 = (float)yi + ((yi < 2) ? -2.f : -1.f);
    const float d2 = sqrtf(d0 * d0 + d1 * d1);
    const float q0 = lrelu(s0g[0] * d0 + s0g[1] * d1 + s0g[2] * d2);
    const float q1 = lrelu(s0g[3] * d0 + s0g[4] * d1 + s0g[5] * d2);
    const float q2 = lrelu(s0g[6] * d0 + s0g[7] * d1 + s0g[8] * d2);
    const float u0 = lrelu(s1g[0] * q0 + s1g[1] * q1 + s1g[2] * q2);
    const float u1 = lrelu(s1g[3] * q0 + s1g[4] * q1 + s1g[5] * q2);
    const float wt2 = lrelu(s2g[0] * u0 + s2g[1] * u1);
    const float awf0 = fabsf(wfg[0]), awf1 = fabsf(wfg[1]);

    // ---- LDS bounce offsets (short units), XOR-swizzled 16B chunks ----
    const int s4  = (px ^ (px >> 2)) & 3;
    short* zb = &zbuf[widx][0];
    const int row = px * 32;
    const int wza = row + ((((g >> 1)       ^ s4) & 3) << 3) + ((g & 1) << 2); // z1 o=4g..+3 / z2
    const int wzb = row + (((((g >> 1) + 2) ^ s4) & 3) << 3) + ((g & 1) << 2); // z1 o=16+4g..+3
    const int rb2 = row + (((g       ^ s4) & 3) << 3);                          // B2: o 8g..8g+7
    const int rb3 = row + ((((g & 1) ^ s4) & 3) << 3);                          // B3: k 8g..8g+7 (g<2)

    // ---- per-lane load indices (advance by immediate per tile) ----
    const int cb = (g & 1) << 3;      // channel base 0 or 8
    int hr_idx[8], lr_idx[8];
    #pragma unroll
    for (int j = 0; j < 8; ++j) {
        hr_idx[j] = (cb + j) * HW  + y * W + xw + px;
        lr_idx[j] = (cb + j) * LHW + (y >> 2) * 256 + (xw >> 2) + (px >> 2);
    }
    const int oidx = y * W + xw + px;
    const bool lo = (g < 2);
    const f32x4 zf = {0.f, 0.f, 0.f, 0.f};

    #pragma unroll
    for (int tt = 0; tt < 8; ++tt) {
        float lrv[8], hrv[8];
        #pragma unroll
        for (int j = 0; j < 8; ++j) {
            hrv[j] = hr[hr_idx[j] + tt * 16];
            lrv[j] = lr[lr_idx[j] + tt * 4];
        }
        // feature B-frags: chunk0 = [lr | hr], chunk1 = [lr*hr | (lr-hr)^2]
        B8 b0, b1;
        #pragma unroll
        for (int j = 0; j < 4; ++j) {
            float ua = lo ? lrv[2 * j]     : hrv[2 * j];
            float ub = lo ? lrv[2 * j + 1] : hrv[2 * j + 1];
            b0.p[j] = cvt2(ua, ub);
            float da = lrv[2 * j]     - hrv[2 * j];
            float db = lrv[2 * j + 1] - hrv[2 * j + 1];
            float pa = lo ? lrv[2 * j]     * hrv[2 * j]     : da * da;
            float pb = lo ? lrv[2 * j + 1] * hrv[2 * j + 1] : db * db;
            b1.p[j] = cvt2(pa, pb);
        }
        // L1: z1[32][16px]
        f32x4 acc1a = __builtin_amdgcn_mfma_f32_16x16x32_bf16(a1[0][0].v, b0.v, zf, 0, 0, 0);
        acc1a = __builtin_amdgcn_mfma_f32_16x16x32_bf16(a1[0][1].v, b1.v, acc1a, 0, 0, 0);
        f32x4 acc1b = __builtin_amdgcn_mfma_f32_16x16x32_bf16(a1[1][0].v, b0.v, zf, 0, 0, 0);
        acc1b = __builtin_amdgcn_mfma_f32_16x16x32_bf16(a1[1][1].v, b1.v, acc1b, 0, 0, 0);
        B4 za, zbp;
        za.p[0]  = cvt2(lrelu(acc1a.x), lrelu(acc1a.y));
        za.p[1]  = cvt2(lrelu(acc1a.z), lrelu(acc1a.w));
        zbp.p[0] = cvt2(lrelu(acc1b.x), lrelu(acc1b.y));
        zbp.p[1] = cvt2(lrelu(acc1b.z), lrelu(acc1b.w));
        *(s16x4*)&zb[wza] = za.v;
        *(s16x4*)&zb[wzb] = zbp.v;
        // L2: z2[16][16px]
        bf16x8 bz1 = *(const bf16x8*)&zb[rb2];
        f32x4 acc2 = __builtin_amdgcn_mfma_f32_16x16x32_bf16(a2.v, bz1, zf, 0, 0, 0);
        B4 z2p;
        z2p.p[0] = cvt2(lrelu(acc2.x), lrelu(acc2.y));
        z2p.p[1] = cvt2(lrelu(acc2.z), lrelu(acc2.w));
        *(s16x4*)&zb[wza] = z2p.v;
        // L3: z3[8][16px]  (A zero-padded; g>=2 garbage*0 = 0)
        bf16x8 bz2 = *(const bf16x8*)&zb[rb3];
        f32x4 acc3 = __builtin_amdgcn_mfma_f32_16x16x32_bf16(a3.v, bz2, zf, 0, 0, 0);
        // L4 + fuse
        float part = w3v.x * lrelu(acc3.x) + w3v.y * lrelu(acc3.y)
                   + w3v.z * lrelu(acc3.z) + w3v.w * lrelu(acc3.w);
        float sum = part + __shfl_xor(part, 16, 64);
        float wt1 = lrelu(sum);
        float res = lrelu(awf0 * wt1 + awf1 * wt2);
        if (g == 0) out[oidx + tt * 16] = res;
    }
}

extern "C" void kernel_launch(void* const* d_in, const int* in_sizes, int n_in,
                              void* d_out, int out_size, void* d_ws, size_t ws_size,
                              hipStream_t stream) {
    const float* lr = (const float*)d_in[0];
    const float* hr = (const float*)d_in[1];
    const float* w0 = (const float*)d_in[2];
    const float* w1 = (const float*)d_in[3];
    const float* w2 = (const float*)d_in[4];
    const float* w3 = (const float*)d_in[5];
    const float* s0 = (const float*)d_in[6];
    const float* s1 = (const float*)d_in[7];
    const float* s2 = (const float*)d_in[8];
    const float* wf = (const float*)d_in[9];
    float* o = (float*)d_out;

    // 65536 16-px tiles / 8 per wave = 8192 waves = 2048 blocks x 256 threads
    ctx_mfma<<<2048, 256, 0, stream>>>(lr, hr, w0, w1, w2, w3, s0, s1, s2, wf, o);
}

// Round 5
// 138.393 us; speedup vs baseline: 22.9630x; 1.0302x over previous
//
#include <hip/hip_runtime.h>
#include <hip/hip_bf16.h>

// context_mapping on MI355X — round 5: MFMA chain + 2-deep software pipeline.
// Round-4 diagnosis: latency-bound (VALU 36%, MFMA 4.5%, HBM 17% — all idle).
// Cause: single LDS bounce buffer serialized all 8 tiles; VGPR=56 meant no
// load hoisting. Fix: (a) parity double-buffer as TWO distinct __shared__
// objects (provably non-aliasing -> compiler can overlap tiles), (b) explicit
// 2-stage load pipeline with named register sets (static indexing), (c) z2 in
// its own subregion (kills within-tile wza-reuse false dep).

typedef __attribute__((ext_vector_type(8))) short bf16x8;
typedef __attribute__((ext_vector_type(4))) short s16x4;
typedef __attribute__((ext_vector_type(4))) float f32x4;

union B8 { bf16x8 v; short2 p[4]; };
union B4 { s16x4 v; short2 p[2]; };

__device__ __forceinline__ float lrelu(float x) { return fmaxf(x, 0.01f * x); }

__device__ __forceinline__ short2 cvt2(float a, float b) {
    __hip_bfloat162 h = __float22bfloat162_rn(make_float2(a, b));
    short2 s; __builtin_memcpy(&s, &h, 4); return s;
}

__global__ __launch_bounds__(256) void ctx_mfma(
    const float* __restrict__ lr,  const float* __restrict__ hr,
    const float* __restrict__ w0g, const float* __restrict__ w1g,
    const float* __restrict__ w2g, const float* __restrict__ w3g,
    const float* __restrict__ s0g, const float* __restrict__ s1g,
    const float* __restrict__ s2g, const float* __restrict__ wfg,
    float* __restrict__ out)
{
    constexpr int W = 1024, HW = 1024 * 1024, LHW = 256 * 256;
    // Two distinct objects -> provable non-aliasing between tile parities.
    // Layout per wave: [0..511] z1 (32rows x 16px bf16), [512..767] z2 (16x16).
    __shared__ __align__(16) short zbufA[4][768];
    __shared__ __align__(16) short zbufB[4][768];

    const int tid  = threadIdx.x;
    const int lane = tid & 63;
    const int widx = tid >> 6;
    const int g    = lane >> 4;       // k-group 0..3
    const int px   = lane & 15;       // pixel-in-tile / weight-row index

    const int wave_id = blockIdx.x * 4 + widx;
    const int y  = wave_id >> 3;          // one row per 8 waves
    const int xw = (wave_id & 7) << 7;    // 128-px span

    // ---- weight A-fragments (A[m=px][k=8g+j]) ----
    B8 a1[2][2];                           // L1: [o0-15 / o16-31][k-chunk]
    #pragma unroll
    for (int m = 0; m < 2; ++m)
        #pragma unroll
        for (int q = 0; q < 2; ++q) {
            const float* wp = w0g + (m * 16 + px) * 64 + q * 32 + g * 8;
            #pragma unroll
            for (int j = 0; j < 4; ++j) a1[m][q].p[j] = cvt2(wp[2 * j], wp[2 * j + 1]);
        }
    B8 a2;                                 // L2: W1 [16 x 32]
    {
        const float* wp = w1g + px * 32 + g * 8;
        #pragma unroll
        for (int j = 0; j < 4; ++j) a2.p[j] = cvt2(wp[2 * j], wp[2 * j + 1]);
    }
    B8 a3;                                 // L3: W2 [8 x 16] zero-padded to [16 x 32]
    {
        const bool val = (px < 8) && (g < 2);
        const float* wp = w2g + (px & 7) * 16 + (g & 1) * 8;   // always in-bounds
        const short2 z2s = make_short2(0, 0);
        #pragma unroll
        for (int j = 0; j < 4; ++j) a3.p[j] = val ? cvt2(wp[2 * j], wp[2 * j + 1]) : z2s;
    }
    const float4 w3v = *(const float4*)(w3g + (g & 1) * 4);    // L4 slice per k-group

    // ---- loop-invariant distance-net (depends only on px&3 and y&3) ----
    const int xi = px & 3, yi = y & 3;
    const float d0 = (float)xi + ((xi < 2) ? -2.f : -1.f);
    const float d1 = (float)yi + ((yi < 2) ? -2.f : -1.f);
    const float d2 = sqrtf(d0 * d0 + d1 * d1);
    const float q0 = lrelu(s0g[0] * d0 + s0g[1] * d1 + s0g[2] * d2);
    const float q1 = lrelu(s0g[3] * d0 + s0g[4] * d1 + s0g[5] * d2);
    const float q2 = lrelu(s0g[6] * d0 + s0g[7] * d1 + s0g[8] * d2);
    const float u0 = lrelu(s1g[0] * q0 + s1g[1] * q1 + s1g[2] * q2);
    const float u1 = lrelu(s1g[3] * q0 + s1g[4] * q1 + s1g[5] * q2);
    const float wt2 = lrelu(s2g[0] * u0 + s2g[1] * u1);
    const float awf0 = fabsf(wfg[0]), awf1 = fabsf(wfg[1]);

    // ---- LDS bounce offsets (short units) ----
    // z1: XOR-swizzled 16B chunks (as round 4, verified).
    const int s4  = (px ^ (px >> 2)) & 3;
    const int row = px * 32;
    const int wza = row + ((((g >> 1)       ^ s4) & 3) << 3) + ((g & 1) << 2);
    const int wzb = row + (((((g >> 1) + 2) ^ s4) & 3) << 3) + ((g & 1) << 2);
    const int rb2 = row + (((g       ^ s4) & 3) << 3);
    // z2: own region [512..768), 2x16B chunks per px, pair-swizzled by px&1.
    const int wz2 = 512 + px * 16 + (((g >> 1) ^ (px & 1)) << 3) + ((g & 1) << 2);
    const int rz3 = 512 + px * 16 + ((((g & 1) ^ (px & 1)) & 1) << 3);

    short* zbA = &zbufA[widx][0];
    short* zbB = &zbufB[widx][0];

    // ---- per-lane load indices (advance by immediate per tile) ----
    const int cb = (g & 1) << 3;      // channel base 0 or 8
    int hr_idx[8], lr_idx[8];
    #pragma unroll
    for (int j = 0; j < 8; ++j) {
        hr_idx[j] = (cb + j) * HW  + y * W + xw + px;
        lr_idx[j] = (cb + j) * LHW + (y >> 2) * 256 + (xw >> 2) + (px >> 2);
    }
    const int oidx = y * W + xw + px;
    const bool lo = (g < 2);
    const f32x4 zf = {0.f, 0.f, 0.f, 0.f};

#define LOADT(LV, HV, T)                                                      \
    {                                                                         \
        _Pragma("unroll")                                                     \
        for (int j = 0; j < 8; ++j) {                                         \
            HV[j] = hr[hr_idx[j] + (T) * 16];                                 \
            LV[j] = lr[lr_idx[j] + (T) * 4];                                  \
        }                                                                     \
    }

#define COMPUTE(LV, HV, ZP, T)                                                \
    {                                                                         \
        B8 b0, b1;                                                            \
        _Pragma("unroll")                                                     \
        for (int j = 0; j < 4; ++j) {                                         \
            float ua = lo ? LV[2 * j]     : HV[2 * j];                        \
            float ub = lo ? LV[2 * j + 1] : HV[2 * j + 1];                    \
            b0.p[j] = cvt2(ua, ub);                                           \
            float da = LV[2 * j]     - HV[2 * j];                             \
            float db = LV[2 * j + 1] - HV[2 * j + 1];                         \
            float pa = lo ? LV[2 * j]     * HV[2 * j]     : da * da;          \
            float pb = lo ? LV[2 * j + 1] * HV[2 * j + 1] : db * db;          \
            b1.p[j] = cvt2(pa, pb);                                           \
        }                                                                     \
        f32x4 acc1a = __builtin_amdgcn_mfma_f32_16x16x32_bf16(a1[0][0].v, b0.v, zf, 0, 0, 0); \
        acc1a = __builtin_amdgcn_mfma_f32_16x16x32_bf16(a1[0][1].v, b1.v, acc1a, 0, 0, 0);    \
        f32x4 acc1b = __builtin_amdgcn_mfma_f32_16x16x32_bf16(a1[1][0].v, b0.v, zf, 0, 0, 0); \
        acc1b = __builtin_amdgcn_mfma_f32_16x16x32_bf16(a1[1][1].v, b1.v, acc1b, 0, 0, 0);    \
        B4 za, zq;                                                            \
        za.p[0] = cvt2(lrelu(acc1a.x), lrelu(acc1a.y));                       \
        za.p[1] = cvt2(lrelu(acc1a.z), lrelu(acc1a.w));                       \
        zq.p[0] = cvt2(lrelu(acc1b.x), lrelu(acc1b.y));                       \
        zq.p[1] = cvt2(lrelu(acc1b.z), lrelu(acc1b.w));                       \
        *(s16x4*)&ZP[wza] = za.v;                                             \
        *(s16x4*)&ZP[wzb] = zq.v;                                             \
        bf16x8 bz1 = *(const bf16x8*)&ZP[rb2];                                \
        f32x4 acc2 = __builtin_amdgcn_mfma_f32_16x16x32_bf16(a2.v, bz1, zf, 0, 0, 0); \
        B4 z2q;                                                               \
        z2q.p[0] = cvt2(lrelu(acc2.x), lrelu(acc2.y));                        \
        z2q.p[1] = cvt2(lrelu(acc2.z), lrelu(acc2.w));                        \
        *(s16x4*)&ZP[wz2] = z2q.v;                                            \
        bf16x8 bz2 = *(const bf16x8*)&ZP[rz3];                                \
        f32x4 acc3 = __builtin_amdgcn_mfma_f32_16x16x32_bf16(a3.v, bz2, zf, 0, 0, 0); \
        float part = w3v.x * lrelu(acc3.x) + w3v.y * lrelu(acc3.y)            \
                   + w3v.z * lrelu(acc3.z) + w3v.w * lrelu(acc3.w);           \
        float sum = part + __shfl_xor(part, 16, 64);                          \
        float wt1 = lrelu(sum);                                               \
        float res = lrelu(awf0 * wt1 + awf1 * wt2);                           \
        if (g == 0) out[oidx + (T) * 16] = res;                               \
    }

    // ---- 2-deep software pipeline over 8 tiles ----
    float la[8], ha[8], lb[8], hb[8];
    LOADT(la, ha, 0);
    #pragma unroll
    for (int tt = 0; tt < 8; tt += 2) {
        LOADT(lb, hb, tt + 1);          // issue next-tile loads before chain
        COMPUTE(la, ha, zbA, tt);
        if (tt + 2 < 8) LOADT(la, ha, tt + 2);
        COMPUTE(lb, hb, zbB, tt + 1);
    }
#undef LOADT
#undef COMPUTE
}

extern "C" void kernel_launch(void* const* d_in, const int* in_sizes, int n_in,
                              void* d_out, int out_size, void* d_ws, size_t ws_size,
                              hipStream_t stream) {
    const float* lr = (const float*)d_in[0];
    const float* hr = (const float*)d_in[1];
    const float* w0 = (const float*)d_in[2];
    const float* w1 = (const float*)d_in[3];
    const float* w2 = (const float*)d_in[4];
    const float* w3 = (const float*)d_in[5];
    const float* s0 = (const float*)d_in[6];
    const float* s1 = (const float*)d_in[7];
    const float* s2 = (const float*)d_in[8];
    const float* wf = (const float*)d_in[9];
    float* o = (float*)d_out;

    // 65536 16-px tiles / 8 per wave = 8192 waves = 2048 blocks x 256 threads
    ctx_mfma<<<2048, 256, 0, stream>>>(lr, hr, w0, w1, w2, w3, s0, s1, s2, wf, o);
}